// Round 2
// baseline (3006.908 us; speedup 1.0000x reference)
//
#include <hip/hip_runtime.h>

#define BB 16
#define C_INN 64
#define C_OUTT 64
#define V_INN 40962
#define V_OUTT 163842

constexpr int RSPLIT = 8;
constexpr int R_TOTAL = BB * C_OUTT;      // 1024 output rows (b,o)
constexpr int R_CHUNK = R_TOTAL / RSPLIT; // 128

// ---------------- Pass 1: Y[b][o][u] = sum_c W[o][c]*x[b][c][u] + bias[o] ----
// grid: (ceil(V_IN/256), B), block 256. Thread per input vertex u.
__global__ __launch_bounds__(256) void pass1_gemm(
    const float* __restrict__ x, const float* __restrict__ W,
    const float* __restrict__ bias, float* __restrict__ Y)
{
    __shared__ float sW[C_OUTT * C_INN];   // 16 KB, natural [o][c] layout
    __shared__ float sB[C_OUTT];
    const int t = threadIdx.x;

    for (int i = t; i < C_OUTT * C_INN / 4; i += 256)
        ((float4*)sW)[i] = ((const float4*)W)[i];
    if (t < C_OUTT) sB[t] = bias[t];
    __syncthreads();

    int u = blockIdx.x * 256 + t;
    const int b = blockIdx.y;
    const bool valid = (u < V_INN);
    if (!valid) u = V_INN - 1;  // clamp so speculative loads stay in-bounds

    // Load this thread's x column (64 values, each load coalesced across wave)
    float xv[C_INN];
    const float* xp = x + (size_t)b * C_INN * V_INN + u;
    #pragma unroll
    for (int c = 0; c < C_INN; ++c) xv[c] = xp[(size_t)c * V_INN];

    float* yp = Y + (size_t)b * C_OUTT * V_INN + u;
    for (int o = 0; o < C_OUTT; ++o) {
        float acc = sB[o];
        const float4* wrow = (const float4*)(sW + o * C_INN);  // wave-uniform → LDS broadcast
        #pragma unroll
        for (int c4 = 0; c4 < C_INN / 4; ++c4) {
            float4 w = wrow[c4];
            acc = fmaf(w.x, xv[4 * c4 + 0], acc);
            acc = fmaf(w.y, xv[4 * c4 + 1], acc);
            acc = fmaf(w.z, xv[4 * c4 + 2], acc);
            acc = fmaf(w.w, xv[4 * c4 + 3], acc);
        }
        if (valid) yp[(size_t)o * V_INN] = acc;  // coalesced store
    }
}

// ---------------- Pass 2: out[r][v] = 0.5*(Y[r][i0[v]] + Y[r][i1[v]]) --------
// Thread handles 2 consecutive v (V_OUT/2 = 81921 threads exactly, no tail).
// grid: (ceil(81921/256), RSPLIT); each block-y covers R_CHUNK rows.
__global__ __launch_bounds__(256) void pass2_gather(
    const float* __restrict__ Y, const int* __restrict__ idx,
    float* __restrict__ out)
{
    const int p = blockIdx.x * 256 + threadIdx.x;
    if (p >= V_OUTT / 2) return;

    // idx[4p .. 4p+3]: 4 consecutive int32 = int4, 16B-aligned
    const int4 iv = ((const int4*)idx)[p];
    const int i00 = iv.x, i01 = iv.y;   // v = 2p
    const int i10 = iv.z, i11 = iv.w;   // v = 2p+1

    const float* yrow = Y + (size_t)(blockIdx.y * R_CHUNK) * V_INN;
    float*       op   = out + (size_t)(blockIdx.y * R_CHUNK) * V_OUTT + 2 * p;

    #pragma unroll 2
    for (int r = 0; r < R_CHUNK; ++r) {
        float2 res;
        res.x = 0.5f * (yrow[i00] + yrow[i01]);  // random-in-row gathers, L2-resident row
        res.y = 0.5f * (yrow[i10] + yrow[i11]);
        *(float2*)op = res;                       // coalesced 8B-aligned store
        yrow += V_INN;
        op   += V_OUTT;
    }
}

// ---------------- Fallback (only if ws too small): fused gather+matvec -------
__global__ __launch_bounds__(256) void fused_fallback(
    const float* __restrict__ x, const int* __restrict__ idx,
    const float* __restrict__ W, const float* __restrict__ bias,
    float* __restrict__ out)
{
    __shared__ float sW[C_OUTT * C_INN];
    __shared__ float sB[C_OUTT];
    const int t = threadIdx.x;
    for (int i = t; i < C_OUTT * C_INN / 4; i += 256)
        ((float4*)sW)[i] = ((const float4*)W)[i];
    if (t < C_OUTT) sB[t] = bias[t];
    __syncthreads();

    int v = blockIdx.x * 256 + t;
    const int b = blockIdx.y;
    const bool valid = (v < V_OUTT);
    if (!valid) v = V_OUTT - 1;
    const int i0 = idx[2 * v], i1 = idx[2 * v + 1];

    float xv[C_INN];
    const float* xb = x + (size_t)b * C_INN * V_INN;
    #pragma unroll
    for (int c = 0; c < C_INN; ++c)
        xv[c] = 0.5f * (xb[(size_t)c * V_INN + i0] + xb[(size_t)c * V_INN + i1]);

    float* op = out + (size_t)b * C_OUTT * V_OUTT + v;
    for (int o = 0; o < C_OUTT; ++o) {
        float acc = sB[o];
        const float4* wrow = (const float4*)(sW + o * C_INN);
        #pragma unroll
        for (int c4 = 0; c4 < C_INN / 4; ++c4) {
            float4 w = wrow[c4];
            acc = fmaf(w.x, xv[4 * c4 + 0], acc);
            acc = fmaf(w.y, xv[4 * c4 + 1], acc);
            acc = fmaf(w.z, xv[4 * c4 + 2], acc);
            acc = fmaf(w.w, xv[4 * c4 + 3], acc);
        }
        if (valid) op[(size_t)o * V_OUTT] = acc;
    }
}

extern "C" void kernel_launch(void* const* d_in, const int* in_sizes, int n_in,
                              void* d_out, int out_size, void* d_ws, size_t ws_size,
                              hipStream_t stream) {
    const float* x    = (const float*)d_in[0];
    const int*   idx  = (const int*)d_in[1];   // harness delivers integer inputs as int32
    const float* W    = (const float*)d_in[2];
    const float* bias = (const float*)d_in[3];
    float* out = (float*)d_out;

    const size_t y_bytes = (size_t)BB * C_OUTT * V_INN * sizeof(float);  // 167.8 MB

    if (ws_size >= y_bytes) {
        float* Y = (float*)d_ws;
        dim3 g1((V_INN + 255) / 256, BB);
        pass1_gemm<<<g1, 256, 0, stream>>>(x, W, bias, Y);
        dim3 g2((V_OUTT / 2 + 255) / 256, RSPLIT);
        pass2_gather<<<g2, 256, 0, stream>>>(Y, idx, out);
    } else {
        dim3 g((V_OUTT + 255) / 256, BB);
        fused_fallback<<<g, 256, 0, stream>>>(x, idx, W, bias, out);
    }
}